// Round 9
// baseline (389.256 us; speedup 1.0000x reference)
//
#include <hip/hip_runtime.h>
#include <hip/hip_bf16.h>

#define NN 50000
#define EE 800000
#define SCAN_BLOCKS 196   // 196*256 = 50176 >= NN

typedef __bf16 bf16x8_t __attribute__((ext_vector_type(8)));
typedef float f32x4_t __attribute__((ext_vector_type(4)));

__device__ __forceinline__ float silu_f(float v) {
    // v * 1/(1+exp(-v)) with v_rcp_f32 (avoids the ~9-instr precise-div sequence)
    return v * __builtin_amdgcn_rcpf(1.0f + __expf(-v));
}

__device__ __forceinline__ float bf_lo(unsigned u) { return __uint_as_float(u << 16); }
__device__ __forceinline__ float bf_hi(unsigned u) { return __uint_as_float(u & 0xffff0000u); }

// ---------------- prep: x -> bf16 (vectorized), weights -> k-slice-major bf16, dst histogram ----------------
// WyS layout: [ks(4)][h(256)][chunk(32)] bf16 for the per-node y GEMM:
//   h<128 -> y_a (x[dst] part, We1 rows 0..127), h>=128 -> y_b (x[src] part, rows 128..255)
// We2S/Wn2S layout: [ks(4)][row(128)][chunk(32)] bf16; Wn1S: [ks(8)][row(128)][chunk(32)]
__global__ void prep_kernel(const float* __restrict__ x,
                            const float* __restrict__ We1,
                            const float* __restrict__ We2,
                            const float* __restrict__ Wn1,
                            const float* __restrict__ Wn2,
                            const int* __restrict__ eidx,
                            __bf16* __restrict__ xb,
                            __bf16* __restrict__ WyS,
                            __bf16* __restrict__ We2S,
                            __bf16* __restrict__ Wn1S,
                            __bf16* __restrict__ Wn2S,
                            int* __restrict__ hist) {
    int tid = blockIdx.x * blockDim.x + threadIdx.x;
    int np = gridDim.x * blockDim.x;
    const int NX8 = NN * 16;                      // groups of 8 floats
    for (int i = tid; i < NX8; i += np) {
        float4 v0 = ((const float4*)x)[(size_t)i * 2];
        float4 v1 = ((const float4*)x)[(size_t)i * 2 + 1];
        union { __bf16 h[8]; uint4 u; } pk;
        pk.h[0] = (__bf16)v0.x; pk.h[1] = (__bf16)v0.y;
        pk.h[2] = (__bf16)v0.z; pk.h[3] = (__bf16)v0.w;
        pk.h[4] = (__bf16)v1.x; pk.h[5] = (__bf16)v1.y;
        pk.h[6] = (__bf16)v1.z; pk.h[7] = (__bf16)v1.w;
        ((uint4*)xb)[i] = pk.u;
    }
    for (int i = tid; i < 256 * 128; i += np) {
        int k = i >> 7, n = i & 127;
        int h = (k < 128) ? n : (128 + n);
        int k2 = k & 127;
        WyS[(k2 >> 5) * 8192 + h * 32 + (k2 & 31)] = (__bf16)We1[i];
        Wn1S[(k >> 5) * 4096 + n * 32 + (k & 31)] = (__bf16)Wn1[i];
    }
    for (int i = tid; i < 128 * 128; i += np) {
        int k = i >> 7, n = i & 127;
        We2S[(k >> 5) * 4096 + n * 32 + (k & 31)] = (__bf16)We2[i];
        Wn2S[(k >> 5) * 4096 + n * 32 + (k & 31)] = (__bf16)Wn2[i];
    }
    for (int i = tid; i < EE; i += np) {
        atomicAdd(&hist[eidx[EE + i]], 1);
    }
}

// ---------------- per-node y GEMM v3: operand-swapped, bf16 split output, be1 folded into ya ----------------
__global__ __launch_bounds__(256, 3)
void ygemm_kernel(const __bf16* __restrict__ xb,
                  const __bf16* __restrict__ WyS,
                  const float* __restrict__ be1,
                  __bf16* __restrict__ ya,
                  __bf16* __restrict__ yb) {
    __shared__ __align__(16) __bf16 Wy[256 * 32];   // 16 KB, XOR-swizzled chunks

    const int t = threadIdx.x;
    const int r0 = blockIdx.x * 64;
    const int w = t >> 6;
    const int lane = t & 63;
    const int m_ = lane & 15;
    const int q = lane >> 4;

    const int node = r0 + w * 16 + m_;
    const long nrow = (long)(node < NN ? node : NN - 1) * 128;

    f32x4_t acc[16];
#pragma unroll
    for (int ot = 0; ot < 16; ++ot) acc[ot] = (f32x4_t){0.f, 0.f, 0.f, 0.f};

    const int wrow = t >> 2;                        // 0..63
    const int pch = (t & 3) ^ ((wrow >> 1) & 3);
    const int wofs = wrow * 32 + pch * 8;
    const int rofs = m_ * 32 + (q ^ ((m_ >> 1) & 3)) * 8;

    bf16x8_t xf = *(const bf16x8_t*)(xb + nrow + q * 8);
    uint4 v0 = *(const uint4*)(WyS + t * 8);
    uint4 v1 = *(const uint4*)(WyS + 2048 + t * 8);
    uint4 v2 = *(const uint4*)(WyS + 4096 + t * 8);
    uint4 v3 = *(const uint4*)(WyS + 6144 + t * 8);
#pragma unroll
    for (int ks = 0; ks < 4; ++ks) {
        __syncthreads();                 // prior Wy reads done
        *(uint4*)(Wy + wofs) = v0;
        *(uint4*)(Wy + 64 * 32 + wofs) = v1;
        *(uint4*)(Wy + 128 * 32 + wofs) = v2;
        *(uint4*)(Wy + 192 * 32 + wofs) = v3;
        __syncthreads();                 // Wy ready
        bf16x8_t nxf;
        if (ks < 3) {                    // prefetch during MFMA phase
            v0 = *(const uint4*)(WyS + (ks + 1) * 8192 + t * 8);
            v1 = *(const uint4*)(WyS + (ks + 1) * 8192 + 2048 + t * 8);
            v2 = *(const uint4*)(WyS + (ks + 1) * 8192 + 4096 + t * 8);
            v3 = *(const uint4*)(WyS + (ks + 1) * 8192 + 6144 + t * 8);
            nxf = *(const bf16x8_t*)(xb + nrow + (ks + 1) * 32 + q * 8);
        }
#pragma unroll
        for (int ot = 0; ot < 16; ++ot) {
            bf16x8_t wf = *(const bf16x8_t*)(Wy + ot * (16 * 32) + rofs);
            acc[ot] = __builtin_amdgcn_mfma_f32_16x16x32_bf16(wf, xf, acc[ot], 0, 0, 0);
        }
        if (ks < 3) xf = nxf;
    }

    if (node < NN) {
#pragma unroll
        for (int ot = 0; ot < 16; ++ot) {
            int col = (ot & 7) * 16 + q * 4;
            float4 b1 = make_float4(0.f, 0.f, 0.f, 0.f);
            if (ot < 8) b1 = *(const float4*)(be1 + col);   // fold bias into ya only
            union { __bf16 h[4]; uint2 u; } pk;
            pk.h[0] = (__bf16)(acc[ot][0] + b1.x);
            pk.h[1] = (__bf16)(acc[ot][1] + b1.y);
            pk.h[2] = (__bf16)(acc[ot][2] + b1.z);
            pk.h[3] = (__bf16)(acc[ot][3] + b1.w);
            __bf16* dst = (ot < 8 ? ya : yb) + (long)node * 128 + col;
            *(uint2*)dst = pk.u;
        }
    }
}

// ---------------- counting-sort scan (3 tiny kernels) ----------------
__global__ void scan_a(const int* __restrict__ hist, int* __restrict__ bsum) {
    __shared__ int sh[256];
    int i = blockIdx.x * 256 + threadIdx.x;
    sh[threadIdx.x] = (i < NN) ? hist[i] : 0;
    __syncthreads();
    for (int s = 128; s > 0; s >>= 1) {
        if (threadIdx.x < s) sh[threadIdx.x] += sh[threadIdx.x + s];
        __syncthreads();
    }
    if (threadIdx.x == 0) bsum[blockIdx.x] = sh[0];
}

__global__ void scan_b(int* __restrict__ bsum) {
    __shared__ int sh[SCAN_BLOCKS];
    int t = threadIdx.x;
    if (t < SCAN_BLOCKS) sh[t] = bsum[t];
    __syncthreads();
    if (t == 0) {
        int acc = 0;
        for (int i = 0; i < SCAN_BLOCKS; ++i) { int v = sh[i]; sh[i] = acc; acc += v; }
    }
    __syncthreads();
    if (t < SCAN_BLOCKS) bsum[t] = sh[t];
}

__global__ void scan_c(const int* __restrict__ hist, const int* __restrict__ bsum,
                       int* __restrict__ off, int* __restrict__ cursor) {
    __shared__ int sh[256];
    int tx = threadIdx.x;
    int i = blockIdx.x * 256 + tx;
    int v = (i < NN) ? hist[i] : 0;
    sh[tx] = v;
    __syncthreads();
    for (int s = 1; s < 256; s <<= 1) {
        int add = (tx >= s) ? sh[tx - s] : 0;
        __syncthreads();
        sh[tx] += add;
        __syncthreads();
    }
    int excl = sh[tx] - v + bsum[blockIdx.x];
    if (i < NN) { off[i] = excl; cursor[i] = excl; }
    if (i == NN - 1) off[NN] = excl + v;
}

// ---------------- scatter: build sorted 32B per-edge records (1 cache line per edge) ----------------
// erec[p] = {dx,dy,dz,r2 | si,di,ea,sg} as two adjacent uint4 (always one 64B line).
__global__ void scatter_kernel(const int* __restrict__ eidx,
                               const float* __restrict__ pos,
                               const float* __restrict__ eattr,
                               const float* __restrict__ s,
                               int* __restrict__ cursor,
                               uint4* __restrict__ erec) {
    int i = blockIdx.x * blockDim.x + threadIdx.x;
    if (i < EE) {
        int si = eidx[i];
        int di = eidx[EE + i];
        int p = atomicAdd(&cursor[di], 1);
        float dx = pos[di * 3 + 0] - pos[si * 3 + 0];
        float dy = pos[di * 3 + 1] - pos[si * 3 + 1];
        float dz = pos[di * 3 + 2] - pos[si * 3 + 2];
        float r2 = dx * dx + dy * dy + dz * dz;
        uint4 a = make_uint4(__float_as_uint(dx), __float_as_uint(dy),
                             __float_as_uint(dz), __float_as_uint(r2));
        uint4 b = make_uint4((unsigned)si, (unsigned)di,
                             __float_as_uint(eattr[i]), __float_as_uint(s[si]));
        erec[(size_t)p * 2] = a;
        erec[(size_t)p * 2 + 1] = b;
    }
}

// ---------------- edge kernel v13: v12 + full We2S hoist above phase-1 (T14 issue-early) ----------------
// block = 256 threads (4 waves), tile = 128 sorted edges.
// All 8 We2S slice-loads (32 VGPRs) issue BEFORE phase-1; the ~2-3us gather/silu phase
// covers their ~600cy latency, so phase-2's barrier vmcnt(0) drains are free.
// r5/r7 lessons: natural-order loop, s_pk via LDS, no XCD swizzle (ya/yb L3-fit).
__global__ __launch_bounds__(256, 3)
void edge_kernel(const __bf16* __restrict__ ya,
                 const __bf16* __restrict__ yb,
                 const uint4* __restrict__ erec,
                 const float* __restrict__ We1,   // f32, rows 256/257 (r2, edge_attr)
                 const __bf16* __restrict__ We2S,
                 const float* __restrict__ be2,
                 const float* __restrict__ Wc,
                 const float* __restrict__ bc,
                 float* __restrict__ msum,
                 float* __restrict__ coordsum) {
    __shared__ __align__(16) __bf16 Wt[128 * 32];   //  8,192 B
    __shared__ __align__(16) __bf16 A2[128 * 136];  // 34,816 B; Mf (f32 64x132) aliases
    __shared__ __align__(16) float4 s_pk[128];      //  2,048 B {r2, ea, src, dst}
    __shared__ float s_sg[128], s_g[128];
    __shared__ float s_diff[128 * 3];
    __shared__ int s_dst[128];

    float* Mf = (float*)A2;

    const int t = threadIdx.x;
    const int e0 = blockIdx.x * 128;
    const int w = t >> 6;
    const int lane = t & 63;
    const int m_ = lane & 15;
    const int q = lane >> 4;

    // per-edge scalars: one 32B record per edge, coalesced
    if (t < 128) {
        const uint4* er = erec + (size_t)(e0 + t) * 2;
        uint4 a = er[0];
        uint4 b = er[1];
        s_diff[t * 3 + 0] = __uint_as_float(a.x);
        s_diff[t * 3 + 1] = __uint_as_float(a.y);
        s_diff[t * 3 + 2] = __uint_as_float(a.z);
        s_pk[t] = make_float4(__uint_as_float(a.w), __uint_as_float(b.z),
                              __uint_as_float(b.x), __uint_as_float(b.y));
        s_sg[t] = __uint_as_float(b.w);
        s_dst[t] = (int)b.y;
    }
    __syncthreads();

    const int el0 = w * 16 + m_;
    const int el1 = 64 + w * 16 + m_;

    // hoisted We2S loads: all 4 k-slices x 2 halves, live across phase-1 (static-indexed)
    uint4 w2[8];
#pragma unroll
    for (int j = 0; j < 8; ++j)
        w2[j] = *(const uint4*)(We2S + j * 2048 + t * 8);   // j = ks*2 + half

    // ---- phase 1: element-wise layer 1 (natural order, FULL unroll -> deep gather pipeline) ----
    {
        const int c8 = (t & 15) * 8;     // 8-col chunk
        const int eb = t >> 4;           // 0..15
        float4 w6a = *(const float4*)(We1 + 256 * 128 + c8);
        float4 w6b = *(const float4*)(We1 + 256 * 128 + c8 + 4);
        float4 w7a = *(const float4*)(We1 + 257 * 128 + c8);
        float4 w7b = *(const float4*)(We1 + 257 * 128 + c8 + 4);
#pragma unroll
        for (int i = 0; i < 8; ++i) {
            int e = eb + i * 16;
            float4 pk4 = s_pk[e];
            float r2 = pk4.x, ea = pk4.y;
            int sn = __float_as_int(pk4.z);
            int dn = __float_as_int(pk4.w);
            uint4 av = *(const uint4*)(ya + (long)dn * 128 + c8);
            uint4 bv = *(const uint4*)(yb + (long)sn * 128 + c8);
            union { __bf16 h[8]; uint4 u; } pk;
            float s0, s1;
            s0 = bf_lo(av.x) + bf_lo(bv.x); pk.h[0] = (__bf16)silu_f(s0 + r2 * w6a.x + ea * w7a.x);
            s1 = bf_hi(av.x) + bf_hi(bv.x); pk.h[1] = (__bf16)silu_f(s1 + r2 * w6a.y + ea * w7a.y);
            s0 = bf_lo(av.y) + bf_lo(bv.y); pk.h[2] = (__bf16)silu_f(s0 + r2 * w6a.z + ea * w7a.z);
            s1 = bf_hi(av.y) + bf_hi(bv.y); pk.h[3] = (__bf16)silu_f(s1 + r2 * w6a.w + ea * w7a.w);
            s0 = bf_lo(av.z) + bf_lo(bv.z); pk.h[4] = (__bf16)silu_f(s0 + r2 * w6b.x + ea * w7b.x);
            s1 = bf_hi(av.z) + bf_hi(bv.z); pk.h[5] = (__bf16)silu_f(s1 + r2 * w6b.y + ea * w7b.y);
            s0 = bf_lo(av.w) + bf_lo(bv.w); pk.h[6] = (__bf16)silu_f(s0 + r2 * w6b.z + ea * w7b.z);
            s1 = bf_hi(av.w) + bf_hi(bv.w); pk.h[7] = (__bf16)silu_f(s1 + r2 * w6b.w + ea * w7b.w);
            *(uint4*)(A2 + e * 136 + c8) = pk.u;
        }
    }

    f32x4_t acc[2][8];
#pragma unroll
    for (int et = 0; et < 2; ++et)
#pragma unroll
        for (int ot = 0; ot < 8; ++ot) acc[et][ot] = (f32x4_t){0.f, 0.f, 0.f, 0.f};

    // staging addresses (XOR-swizzled, coalesced; see r2 notes)
    const int wrow = t >> 2;
    const int pch = (t & 3) ^ ((wrow >> 1) & 3);
    const int wofs = wrow * 32 + pch * 8;
    const int rofs = m_ * 32 + (q ^ ((m_ >> 1) & 3)) * 8;

    // ---- phase 2: layer 2, K = 128, B-operand = A2 rows (same-wave LDS) ----
#pragma unroll
    for (int ks = 0; ks < 4; ++ks) {
        __syncthreads();                 // A2 writes (ks=0) / prior wf reads
        *(uint4*)(Wt + wofs) = w2[ks * 2];
        *(uint4*)(Wt + 64 * 32 + wofs) = w2[ks * 2 + 1];
        __syncthreads();                 // Wt ready
        bf16x8_t af0 = *(const bf16x8_t*)(A2 + el0 * 136 + ks * 32 + q * 8);
        bf16x8_t af1 = *(const bf16x8_t*)(A2 + el1 * 136 + ks * 32 + q * 8);
#pragma unroll
        for (int ot = 0; ot < 8; ++ot) {
            bf16x8_t wf = *(const bf16x8_t*)(Wt + ot * (16 * 32) + rofs);
            acc[0][ot] = __builtin_amdgcn_mfma_f32_16x16x32_bf16(wf, af0, acc[0][ot], 0, 0, 0);
            acc[1][ot] = __builtin_amdgcn_mfma_f32_16x16x32_bf16(wf, af1, acc[1][ot], 0, 0, 0);
        }
    }

    // epilogue 2: + b, SiLU, * s[src]; gamma via q-lane shuffle reduce
    {
        float sg0 = s_sg[el0], sg1 = s_sg[el1];
        float gp0 = 0.f, gp1 = 0.f;
#pragma unroll
        for (int ot = 0; ot < 8; ++ot) {
            int oc = ot * 16 + q * 4;
            float4 b2 = *(const float4*)(be2 + oc);
            float4 wc = *(const float4*)(Wc + oc);
            f32x4_t v0_ = acc[0][ot], v1_ = acc[1][ot];
            v0_[0] = silu_f(v0_[0] + b2.x) * sg0; v0_[1] = silu_f(v0_[1] + b2.y) * sg0;
            v0_[2] = silu_f(v0_[2] + b2.z) * sg0; v0_[3] = silu_f(v0_[3] + b2.w) * sg0;
            v1_[0] = silu_f(v1_[0] + b2.x) * sg1; v1_[1] = silu_f(v1_[1] + b2.y) * sg1;
            v1_[2] = silu_f(v1_[2] + b2.z) * sg1; v1_[3] = silu_f(v1_[3] + b2.w) * sg1;
            acc[0][ot] = v0_; acc[1][ot] = v1_;
            gp0 += v0_[0] * wc.x + v0_[1] * wc.y + v0_[2] * wc.z + v0_[3] * wc.w;
            gp1 += v1_[0] * wc.x + v1_[1] * wc.y + v1_[2] * wc.z + v1_[3] * wc.w;
        }
        gp0 += __shfl_xor(gp0, 16); gp0 += __shfl_xor(gp0, 32);
        gp1 += __shfl_xor(gp1, 16); gp1 += __shfl_xor(gp1, 32);
        if (q == 0) {
            float b0 = bc[0];
            s_g[el0] = gp0 + b0;
            s_g[el1] = gp1 + b0;
        }
    }
    __syncthreads();   // P0: all A2 reads done (Mf aliases), s_g visible

    // coord: 24 threads, 3 axes x 8 row-chunks of 16 (atomics make chunk splits safe)
    if (t < 24) {
        int ax = t % 3, ch = t / 3;
        int base = ch * 16;
        float run = 0.f;
        int cur = s_dst[base];
        for (int r = 0; r < 16; ++r) {
            int rr = base + r;
            int d = s_dst[rr];
            if (d != cur) {
                atomicAdd(&coordsum[cur * 3 + ax], run);
                run = 0.f; cur = d;
            }
            run += s_g[rr] * s_diff[rr * 3 + ax];
        }
        atomicAdd(&coordsum[cur * 3 + ax], run);
    }

    // msum: two phases of 64 edges; all 256 threads (col x row-half), serial length 32
#pragma unroll
    for (int ph = 0; ph < 2; ++ph) {
        int lr = w * 16 + m_;
#pragma unroll
        for (int ot = 0; ot < 8; ++ot)
            *(f32x4_t*)(Mf + lr * 132 + ot * 16 + q * 4) = acc[ph][ot];
        __syncthreads();   // Mf complete
        {
            int c = t & 127;
            int half = t >> 7;               // wave-uniform (waves 0,1 -> 0; 2,3 -> 1)
            int base = ph * 64 + half * 32;
            float run = 0.f;
            int cur = s_dst[base];
            for (int r = 0; r < 32; ++r) {
                int d = s_dst[base + r];     // wave-uniform branch
                if (d != cur) {
                    atomicAdd(&msum[(long)cur * 128 + c], run);
                    run = 0.f; cur = d;
                }
                run += Mf[(half * 32 + r) * 132 + c];
            }
            atomicAdd(&msum[(long)cur * 128 + c], run);
        }
        __syncthreads();   // reduce done before Mf overwrite / exit
    }
}

// ---------------- node kernel v2: operand-swapped, no Abf staging, 4 blocks/CU ----------------
__global__ __launch_bounds__(256, 4)
void node_kernel(const __bf16* __restrict__ xb,
                 const float* __restrict__ msum,
                 const int* __restrict__ off,
                 const __bf16* __restrict__ Wn1S,
                 const float* __restrict__ bn1,
                 const __bf16* __restrict__ Wn2S,
                 const float* __restrict__ bn2,
                 const float* __restrict__ pos,
                 const float* __restrict__ csum,
                 float* __restrict__ xout,
                 float* __restrict__ pout) {
    __shared__ __align__(16) __bf16 Wt[128 * 32];   //  8,192 B
    __shared__ __align__(16) __bf16 A2[64 * 136];   // 17,408 B

    const int t = threadIdx.x;
    const int r0 = blockIdx.x * 64;
    const int w = t >> 6;
    const int lane = t & 63;
    const int m_ = lane & 15;
    const int q = lane >> 4;

    // pos update for this block's 64 nodes (independent of the MLP)
    if (t < 192) {
        int node = r0 + t / 3;
        if (node < NN) {
            int dg = off[node + 1] - off[node];
            float inv = 1.f / (float)(dg < 1 ? 1 : dg);
            int fl = node * 3 + t % 3;
            pout[fl] = pos[fl] + csum[fl] * inv;
        }
    }

    const int node = r0 + w * 16 + m_;
    const int ncl = node < NN ? node : NN - 1;
    const long nrow = (long)ncl * 128;
    const int dg = off[ncl + 1] - off[ncl];
    const float inv = 1.f / (float)(dg < 1 ? 1 : dg);

    f32x4_t acc[8];
#pragma unroll
    for (int ot = 0; ot < 8; ++ot) acc[ot] = (f32x4_t){0.f, 0.f, 0.f, 0.f};

    const int wrow = t >> 2;
    const int pch = (t & 3) ^ ((wrow >> 1) & 3);
    const int wofs = wrow * 32 + pch * 8;
    const int rofs = m_ * 32 + (q ^ ((m_ >> 1) & 3)) * 8;

    // ---- layer 1: K = 256; ks<4 from xb (bf16), ks>=4 from msum*inv (f32->bf16) ----
    bf16x8_t xf = *(const bf16x8_t*)(xb + nrow + q * 8);
    float4 mf0, mf1;
    uint4 v0 = *(const uint4*)(Wn1S + t * 8);
    uint4 v1 = *(const uint4*)(Wn1S + 2048 + t * 8);
#pragma unroll
    for (int ks = 0; ks < 8; ++ks) {
        __syncthreads();                 // prior Wt reads done
        *(uint4*)(Wt + wofs) = v0;
        *(uint4*)(Wt + 64 * 32 + wofs) = v1;
        __syncthreads();                 // Wt ready
        bf16x8_t nxf; float4 nm0, nm1;
        if (ks < 7) {                    // prefetch next slice + next input fragment
            v0 = *(const uint4*)(Wn1S + (ks + 1) * 4096 + t * 8);
            v1 = *(const uint4*)(Wn1S + (ks + 1) * 4096 + 2048 + t * 8);
            if (ks + 1 < 4) {
                nxf = *(const bf16x8_t*)(xb + nrow + (ks + 1) * 32 + q * 8);
            } else {
                const float* mp = msum + nrow + (ks + 1 - 4) * 32 + q * 8;
                nm0 = *(const float4*)(mp);
                nm1 = *(const float4*)(mp + 4);
            }
        }
        bf16x8_t cf;
        if (ks < 4) {
            cf = xf;
        } else {
            union { __bf16 h[8]; bf16x8_t v; } u;
            u.h[0] = (__bf16)(mf0.x * inv); u.h[1] = (__bf16)(mf0.y * inv);
            u.h[2] = (__bf16)(mf0.z * inv); u.h[3] = (__bf16)(mf0.w * inv);
            u.h[4] = (__bf16)(mf1.x * inv); u.h[5] = (__bf16)(mf1.y * inv);
            u.h[6] = (__bf16)(mf1.z * inv); u.h[7] = (__bf16)(mf1.w * inv);
            cf = u.v;
        }
#pragma unroll
        for (int ot = 0; ot < 8; ++ot) {
            bf16x8_t wf = *(const bf16x8_t*)(Wt + ot * (16 * 32) + rofs);
            acc[ot] = __builtin_amdgcn_mfma_f32_16x16x32_bf16(wf, cf, acc[ot], 0, 0, 0);
        }
        if (ks < 7) {
            if (ks + 1 < 4) xf = nxf;
            else { mf0 = nm0; mf1 = nm1; }
        }
    }

    // epilogue 1: + bn1, SiLU -> A2 (same-wave rows)
#pragma unroll
    for (int ot = 0; ot < 8; ++ot) {
        float4 b1 = *(const float4*)(bn1 + ot * 16 + q * 4);
        union { __bf16 h[4]; uint2 u; } pk;
        pk.h[0] = (__bf16)silu_f(acc[ot][0] + b1.x);
        pk.h[1] = (__bf16)silu_f(acc[ot][1] + b1.y);
        pk.h[2] = (__bf16)silu_f(acc[ot][2] + b1.z);
        pk.h[3] = (__bf16)silu_f(acc[ot][3] + b1.w);
        *(uint2*)(A2 + (w * 16 + m_) * 136 + ot * 16 + q * 4) = pk.u;
        acc[ot] = (f32x4_t){0.f, 0.f, 0.f, 0.f};
    }

    // ---- layer 2: K = 128, B-operand = A2 row fragments (same-wave LDS) ----
    uint4 u0 = *(const uint4*)(Wn2S + t * 8);
    uint4 u1 = *(const uint4*)(Wn2S + 2048 + t * 8);
#pragma unroll
    for (int ks = 0; ks < 4; ++ks) {
        __syncthreads();                 // prior Wt reads done
        *(uint4*)(Wt + wofs) = u0;
        *(uint4*)(Wt + 64 * 32 + wofs) = u1;
        __syncthreads();                 // Wt ready
        if (ks < 3) {
            u0 = *(const uint4*)(Wn2S + (ks + 1) * 4096 + t * 8);
            u1 = *(const uint4*)(Wn2S + (ks + 1) * 4096 + 2048 + t * 8);
        }
        bf16x8_t af = *(const bf16x8_t*)(A2 + (w * 16 + m_) * 136 + ks * 32 + q * 8);
#pragma unroll
        for (int ot = 0; ot < 8; ++ot) {
            bf16x8_t wf = *(const bf16x8_t*)(Wt + ot * (16 * 32) + rofs);
            acc[ot] = __builtin_amdgcn_mfma_f32_16x16x32_bf16(wf, af, acc[ot], 0, 0, 0);
        }
    }

    // epilogue 2: + bn2, coalesced float4 stores
    if (node < NN) {
#pragma unroll
        for (int ot = 0; ot < 8; ++ot) {
            float4 b2 = *(const float4*)(bn2 + ot * 16 + q * 4);
            float4 o;
            o.x = acc[ot][0] + b2.x; o.y = acc[ot][1] + b2.y;
            o.z = acc[ot][2] + b2.z; o.w = acc[ot][3] + b2.w;
            *(float4*)(xout + nrow + ot * 16 + q * 4) = o;
        }
    }
}

extern "C" void kernel_launch(void* const* d_in, const int* in_sizes, int n_in,
                              void* d_out, int out_size, void* d_ws, size_t ws_size,
                              hipStream_t stream) {
    const float* x     = (const float*)d_in[0];
    const float* pos   = (const float*)d_in[1];
    const int*   eidx  = (const int*)d_in[2];
    const float* eattr = (const float*)d_in[3];
    const float* s     = (const float*)d_in[4];
    const float* We1   = (const float*)d_in[5];
    const float* be1   = (const float*)d_in[6];
    const float* We2   = (const float*)d_in[7];
    const float* be2   = (const float*)d_in[8];
    const float* Wn1   = (const float*)d_in[9];
    const float* bn1   = (const float*)d_in[10];
    const float* Wn2   = (const float*)d_in[11];
    const float* bn2   = (const float*)d_in[12];
    const float* Wc    = (const float*)d_in[13];
    const float* bc    = (const float*)d_in[14];

    char* ws = (char*)d_ws;
    __bf16* xb     = (__bf16*)(ws);                 // 12,800,000
    __bf16* WyS    = (__bf16*)(ws + 12800000);      //     65,536
    __bf16* We2S   = (__bf16*)(ws + 12865536);      //     32,768
    __bf16* Wn1S   = (__bf16*)(ws + 12898304);      //     65,536
    __bf16* Wn2S   = (__bf16*)(ws + 12963840);      //     32,768
    float*  msum   = (float*)(ws + 12996608);       // 25,600,000
    float*  csum   = (float*)(ws + 38596608);       //    600,000
    int*    hist   = (int*)(ws + 39196608);         //    200,000
    int*    off    = (int*)(ws + 39396608);         //    200,064
    int*    cursor = (int*)(ws + 39596672);         //    200,064
    uint4*  erec   = (uint4*)(ws + 39796736);       // 25,600,000 (32B/edge)
    int*    bsum   = (int*)(ws + 65396736);         //      1,024
    __bf16* ya     = (__bf16*)(ws + 65397760);      // 12,800,000
    __bf16* yb     = (__bf16*)(ws + 78197760);      // 12,800,000 (end 90,997,760)

    float* xout = (float*)d_out;
    float* pout = xout + (size_t)NN * 128;

    // zero msum + csum + hist (contiguous, 26.4 MB)
    hipMemsetAsync(ws + 12996608, 0, 26400000, stream);
    prep_kernel<<<1024, 256, 0, stream>>>(x, We1, We2, Wn1, Wn2, eidx,
                                          xb, WyS, We2S, Wn1S, Wn2S, hist);
    ygemm_kernel<<<(NN + 63) / 64, 256, 0, stream>>>(xb, WyS, be1, ya, yb);
    scan_a<<<SCAN_BLOCKS, 256, 0, stream>>>(hist, bsum);
    scan_b<<<1, 256, 0, stream>>>(bsum);
    scan_c<<<SCAN_BLOCKS, 256, 0, stream>>>(hist, bsum, off, cursor);
    scatter_kernel<<<(EE + 255) / 256, 256, 0, stream>>>(eidx, pos, eattr, s, cursor, erec);
    edge_kernel<<<EE / 128, 256, 0, stream>>>(ya, yb, erec,
                                              We1, We2S, be2, Wc, bc,
                                              msum, csum);
    node_kernel<<<(NN + 63) / 64, 256, 0, stream>>>(xb, msum, off, Wn1S, bn1, Wn2S, bn2,
                                                    pos, csum, xout, pout);
}

// Round 10
// 346.172 us; speedup vs baseline: 1.1245x; 1.1245x over previous
//
#include <hip/hip_runtime.h>
#include <hip/hip_bf16.h>

#define NN 50000
#define EE 800000
#define SCAN_BLOCKS 196   // 196*256 = 50176 >= NN

typedef __bf16 bf16x8_t __attribute__((ext_vector_type(8)));
typedef float f32x4_t __attribute__((ext_vector_type(4)));

__device__ __forceinline__ float silu_f(float v) {
    // v * 1/(1+exp(-v)) with v_rcp_f32 (avoids the ~9-instr precise-div sequence)
    return v * __builtin_amdgcn_rcpf(1.0f + __expf(-v));
}

__device__ __forceinline__ float bf_lo(unsigned u) { return __uint_as_float(u << 16); }
__device__ __forceinline__ float bf_hi(unsigned u) { return __uint_as_float(u & 0xffff0000u); }

// ---------------- prep: x -> bf16 (vectorized), weights -> k-slice-major bf16, dst histogram ----------------
// WyS layout: [ks(4)][h(256)][chunk(32)] bf16 for the per-node y GEMM:
//   h<128 -> y_a (x[dst] part, We1 rows 0..127), h>=128 -> y_b (x[src] part, rows 128..255)
// We2S/Wn2S layout: [ks(4)][row(128)][chunk(32)] bf16; Wn1S: [ks(8)][row(128)][chunk(32)]
__global__ void prep_kernel(const float* __restrict__ x,
                            const float* __restrict__ We1,
                            const float* __restrict__ We2,
                            const float* __restrict__ Wn1,
                            const float* __restrict__ Wn2,
                            const int* __restrict__ eidx,
                            __bf16* __restrict__ xb,
                            __bf16* __restrict__ WyS,
                            __bf16* __restrict__ We2S,
                            __bf16* __restrict__ Wn1S,
                            __bf16* __restrict__ Wn2S,
                            int* __restrict__ hist) {
    int tid = blockIdx.x * blockDim.x + threadIdx.x;
    int np = gridDim.x * blockDim.x;
    const int NX8 = NN * 16;                      // groups of 8 floats
    for (int i = tid; i < NX8; i += np) {
        float4 v0 = ((const float4*)x)[(size_t)i * 2];
        float4 v1 = ((const float4*)x)[(size_t)i * 2 + 1];
        union { __bf16 h[8]; uint4 u; } pk;
        pk.h[0] = (__bf16)v0.x; pk.h[1] = (__bf16)v0.y;
        pk.h[2] = (__bf16)v0.z; pk.h[3] = (__bf16)v0.w;
        pk.h[4] = (__bf16)v1.x; pk.h[5] = (__bf16)v1.y;
        pk.h[6] = (__bf16)v1.z; pk.h[7] = (__bf16)v1.w;
        ((uint4*)xb)[i] = pk.u;
    }
    for (int i = tid; i < 256 * 128; i += np) {
        int k = i >> 7, n = i & 127;
        int h = (k < 128) ? n : (128 + n);
        int k2 = k & 127;
        WyS[(k2 >> 5) * 8192 + h * 32 + (k2 & 31)] = (__bf16)We1[i];
        Wn1S[(k >> 5) * 4096 + n * 32 + (k & 31)] = (__bf16)Wn1[i];
    }
    for (int i = tid; i < 128 * 128; i += np) {
        int k = i >> 7, n = i & 127;
        We2S[(k >> 5) * 4096 + n * 32 + (k & 31)] = (__bf16)We2[i];
        Wn2S[(k >> 5) * 4096 + n * 32 + (k & 31)] = (__bf16)Wn2[i];
    }
    for (int i = tid; i < EE; i += np) {
        atomicAdd(&hist[eidx[EE + i]], 1);
    }
}

// ---------------- per-node y GEMM v3: operand-swapped, bf16 split output, be1 folded into ya ----------------
__global__ __launch_bounds__(256, 3)
void ygemm_kernel(const __bf16* __restrict__ xb,
                  const __bf16* __restrict__ WyS,
                  const float* __restrict__ be1,
                  __bf16* __restrict__ ya,
                  __bf16* __restrict__ yb) {
    __shared__ __align__(16) __bf16 Wy[256 * 32];   // 16 KB, XOR-swizzled chunks

    const int t = threadIdx.x;
    const int r0 = blockIdx.x * 64;
    const int w = t >> 6;
    const int lane = t & 63;
    const int m_ = lane & 15;
    const int q = lane >> 4;

    const int node = r0 + w * 16 + m_;
    const long nrow = (long)(node < NN ? node : NN - 1) * 128;

    f32x4_t acc[16];
#pragma unroll
    for (int ot = 0; ot < 16; ++ot) acc[ot] = (f32x4_t){0.f, 0.f, 0.f, 0.f};

    const int wrow = t >> 2;                        // 0..63
    const int pch = (t & 3) ^ ((wrow >> 1) & 3);
    const int wofs = wrow * 32 + pch * 8;
    const int rofs = m_ * 32 + (q ^ ((m_ >> 1) & 3)) * 8;

    bf16x8_t xf = *(const bf16x8_t*)(xb + nrow + q * 8);
    uint4 v0 = *(const uint4*)(WyS + t * 8);
    uint4 v1 = *(const uint4*)(WyS + 2048 + t * 8);
    uint4 v2 = *(const uint4*)(WyS + 4096 + t * 8);
    uint4 v3 = *(const uint4*)(WyS + 6144 + t * 8);
#pragma unroll
    for (int ks = 0; ks < 4; ++ks) {
        __syncthreads();                 // prior Wy reads done
        *(uint4*)(Wy + wofs) = v0;
        *(uint4*)(Wy + 64 * 32 + wofs) = v1;
        *(uint4*)(Wy + 128 * 32 + wofs) = v2;
        *(uint4*)(Wy + 192 * 32 + wofs) = v3;
        __syncthreads();                 // Wy ready
        bf16x8_t nxf;
        if (ks < 3) {                    // prefetch during MFMA phase
            v0 = *(const uint4*)(WyS + (ks + 1) * 8192 + t * 8);
            v1 = *(const uint4*)(WyS + (ks + 1) * 8192 + 2048 + t * 8);
            v2 = *(const uint4*)(WyS + (ks + 1) * 8192 + 4096 + t * 8);
            v3 = *(const uint4*)(WyS + (ks + 1) * 8192 + 6144 + t * 8);
            nxf = *(const bf16x8_t*)(xb + nrow + (ks + 1) * 32 + q * 8);
        }
#pragma unroll
        for (int ot = 0; ot < 16; ++ot) {
            bf16x8_t wf = *(const bf16x8_t*)(Wy + ot * (16 * 32) + rofs);
            acc[ot] = __builtin_amdgcn_mfma_f32_16x16x32_bf16(wf, xf, acc[ot], 0, 0, 0);
        }
        if (ks < 3) xf = nxf;
    }

    if (node < NN) {
#pragma unroll
        for (int ot = 0; ot < 16; ++ot) {
            int col = (ot & 7) * 16 + q * 4;
            float4 b1 = make_float4(0.f, 0.f, 0.f, 0.f);
            if (ot < 8) b1 = *(const float4*)(be1 + col);   // fold bias into ya only
            union { __bf16 h[4]; uint2 u; } pk;
            pk.h[0] = (__bf16)(acc[ot][0] + b1.x);
            pk.h[1] = (__bf16)(acc[ot][1] + b1.y);
            pk.h[2] = (__bf16)(acc[ot][2] + b1.z);
            pk.h[3] = (__bf16)(acc[ot][3] + b1.w);
            __bf16* dst = (ot < 8 ? ya : yb) + (long)node * 128 + col;
            *(uint2*)dst = pk.u;
        }
    }
}

// ---------------- counting-sort scan (3 tiny kernels) ----------------
__global__ void scan_a(const int* __restrict__ hist, int* __restrict__ bsum) {
    __shared__ int sh[256];
    int i = blockIdx.x * 256 + threadIdx.x;
    sh[threadIdx.x] = (i < NN) ? hist[i] : 0;
    __syncthreads();
    for (int s = 128; s > 0; s >>= 1) {
        if (threadIdx.x < s) sh[threadIdx.x] += sh[threadIdx.x + s];
        __syncthreads();
    }
    if (threadIdx.x == 0) bsum[blockIdx.x] = sh[0];
}

__global__ void scan_b(int* __restrict__ bsum) {
    __shared__ int sh[SCAN_BLOCKS];
    int t = threadIdx.x;
    if (t < SCAN_BLOCKS) sh[t] = bsum[t];
    __syncthreads();
    if (t == 0) {
        int acc = 0;
        for (int i = 0; i < SCAN_BLOCKS; ++i) { int v = sh[i]; sh[i] = acc; acc += v; }
    }
    __syncthreads();
    if (t < SCAN_BLOCKS) bsum[t] = sh[t];
}

__global__ void scan_c(const int* __restrict__ hist, const int* __restrict__ bsum,
                       int* __restrict__ off, int* __restrict__ cursor) {
    __shared__ int sh[256];
    int tx = threadIdx.x;
    int i = blockIdx.x * 256 + tx;
    int v = (i < NN) ? hist[i] : 0;
    sh[tx] = v;
    __syncthreads();
    for (int s = 1; s < 256; s <<= 1) {
        int add = (tx >= s) ? sh[tx - s] : 0;
        __syncthreads();
        sh[tx] += add;
        __syncthreads();
    }
    int excl = sh[tx] - v + bsum[blockIdx.x];
    if (i < NN) { off[i] = excl; cursor[i] = excl; }
    if (i == NN - 1) off[NN] = excl + v;
}

// ---------------- scatter: build sorted 32B per-edge records (1 cache line per edge) ----------------
// erec[p] = {dx,dy,dz,r2 | si,di,ea,sg} as two adjacent uint4 (always one 64B line).
__global__ void scatter_kernel(const int* __restrict__ eidx,
                               const float* __restrict__ pos,
                               const float* __restrict__ eattr,
                               const float* __restrict__ s,
                               int* __restrict__ cursor,
                               uint4* __restrict__ erec) {
    int i = blockIdx.x * blockDim.x + threadIdx.x;
    if (i < EE) {
        int si = eidx[i];
        int di = eidx[EE + i];
        int p = atomicAdd(&cursor[di], 1);
        float dx = pos[di * 3 + 0] - pos[si * 3 + 0];
        float dy = pos[di * 3 + 1] - pos[si * 3 + 1];
        float dz = pos[di * 3 + 2] - pos[si * 3 + 2];
        float r2 = dx * dx + dy * dy + dz * dz;
        uint4 a = make_uint4(__float_as_uint(dx), __float_as_uint(dy),
                             __float_as_uint(dz), __float_as_uint(r2));
        uint4 b = make_uint4((unsigned)si, (unsigned)di,
                             __float_as_uint(eattr[i]), __float_as_uint(s[si]));
        erec[(size_t)p * 2] = a;
        erec[(size_t)p * 2 + 1] = b;
    }
}

// ---------------- edge kernel v12 (FINAL): r6 structure + full-unroll phase-1 ----------------
// block = 256 threads (4 waves), tile = 128 sorted edges.
// phase 1: A2[e][c] = silu(ya[dst][c] + yb[src][c] + r2*w6 + ea*w7)  (be1 pre-folded into ya)
// phase 2: layer 2 MFMA, Wt XOR-swizzled staging, prefetch issued after 2nd barrier.
// Session lessons baked in:
//  r5: no hand-rotated gather pipeline (compiler schedules the natural loop better)
//  r7: s_pk via LDS (per-thread global scalar reads serialize the gather chain);
//      no XCD swizzle (ya/yb are L3-fit -> null, cf. m160)
//  r9: do NOT hoist We2S regs across phase-1 (allocator spills to scratch: +200MB WRITE)
__global__ __launch_bounds__(256, 3)
void edge_kernel(const __bf16* __restrict__ ya,
                 const __bf16* __restrict__ yb,
                 const uint4* __restrict__ erec,
                 const float* __restrict__ We1,   // f32, rows 256/257 (r2, edge_attr)
                 const __bf16* __restrict__ We2S,
                 const float* __restrict__ be2,
                 const float* __restrict__ Wc,
                 const float* __restrict__ bc,
                 float* __restrict__ msum,
                 float* __restrict__ coordsum) {
    __shared__ __align__(16) __bf16 Wt[128 * 32];   //  8,192 B
    __shared__ __align__(16) __bf16 A2[128 * 136];  // 34,816 B; Mf (f32 64x132) aliases
    __shared__ __align__(16) float4 s_pk[128];      //  2,048 B {r2, ea, src, dst}
    __shared__ float s_sg[128], s_g[128];
    __shared__ float s_diff[128 * 3];
    __shared__ int s_dst[128];

    float* Mf = (float*)A2;

    const int t = threadIdx.x;
    const int e0 = blockIdx.x * 128;
    const int w = t >> 6;
    const int lane = t & 63;
    const int m_ = lane & 15;
    const int q = lane >> 4;

    // per-edge scalars: one 32B record per edge, coalesced
    if (t < 128) {
        const uint4* er = erec + (size_t)(e0 + t) * 2;
        uint4 a = er[0];
        uint4 b = er[1];
        s_diff[t * 3 + 0] = __uint_as_float(a.x);
        s_diff[t * 3 + 1] = __uint_as_float(a.y);
        s_diff[t * 3 + 2] = __uint_as_float(a.z);
        s_pk[t] = make_float4(__uint_as_float(a.w), __uint_as_float(b.z),
                              __uint_as_float(b.x), __uint_as_float(b.y));
        s_sg[t] = __uint_as_float(b.w);
        s_dst[t] = (int)b.y;
    }
    __syncthreads();

    const int el0 = w * 16 + m_;
    const int el1 = 64 + w * 16 + m_;

    // ---- phase 1: element-wise layer 1 (natural order, FULL unroll -> deep gather pipeline) ----
    {
        const int c8 = (t & 15) * 8;     // 8-col chunk
        const int eb = t >> 4;           // 0..15
        float4 w6a = *(const float4*)(We1 + 256 * 128 + c8);
        float4 w6b = *(const float4*)(We1 + 256 * 128 + c8 + 4);
        float4 w7a = *(const float4*)(We1 + 257 * 128 + c8);
        float4 w7b = *(const float4*)(We1 + 257 * 128 + c8 + 4);
#pragma unroll
        for (int i = 0; i < 8; ++i) {
            int e = eb + i * 16;
            float4 pk4 = s_pk[e];
            float r2 = pk4.x, ea = pk4.y;
            int sn = __float_as_int(pk4.z);
            int dn = __float_as_int(pk4.w);
            uint4 av = *(const uint4*)(ya + (long)dn * 128 + c8);
            uint4 bv = *(const uint4*)(yb + (long)sn * 128 + c8);
            union { __bf16 h[8]; uint4 u; } pk;
            float s0, s1;
            s0 = bf_lo(av.x) + bf_lo(bv.x); pk.h[0] = (__bf16)silu_f(s0 + r2 * w6a.x + ea * w7a.x);
            s1 = bf_hi(av.x) + bf_hi(bv.x); pk.h[1] = (__bf16)silu_f(s1 + r2 * w6a.y + ea * w7a.y);
            s0 = bf_lo(av.y) + bf_lo(bv.y); pk.h[2] = (__bf16)silu_f(s0 + r2 * w6a.z + ea * w7a.z);
            s1 = bf_hi(av.y) + bf_hi(bv.y); pk.h[3] = (__bf16)silu_f(s1 + r2 * w6a.w + ea * w7a.w);
            s0 = bf_lo(av.z) + bf_lo(bv.z); pk.h[4] = (__bf16)silu_f(s0 + r2 * w6b.x + ea * w7b.x);
            s1 = bf_hi(av.z) + bf_hi(bv.z); pk.h[5] = (__bf16)silu_f(s1 + r2 * w6b.y + ea * w7b.y);
            s0 = bf_lo(av.w) + bf_lo(bv.w); pk.h[6] = (__bf16)silu_f(s0 + r2 * w6b.z + ea * w7b.z);
            s1 = bf_hi(av.w) + bf_hi(bv.w); pk.h[7] = (__bf16)silu_f(s1 + r2 * w6b.w + ea * w7b.w);
            *(uint4*)(A2 + e * 136 + c8) = pk.u;
        }
    }

    f32x4_t acc[2][8];
#pragma unroll
    for (int et = 0; et < 2; ++et)
#pragma unroll
        for (int ot = 0; ot < 8; ++ot) acc[et][ot] = (f32x4_t){0.f, 0.f, 0.f, 0.f};

    // staging addresses (XOR-swizzled, coalesced; see r2 notes)
    const int wrow = t >> 2;
    const int pch = (t & 3) ^ ((wrow >> 1) & 3);
    const int wofs = wrow * 32 + pch * 8;
    const int rofs = m_ * 32 + (q ^ ((m_ >> 1) & 3)) * 8;

    // ---- phase 2: layer 2, K = 128, B-operand = A2 rows (same-wave LDS) ----
    uint4 w20 = *(const uint4*)(We2S + t * 8);
    uint4 w21 = *(const uint4*)(We2S + 2048 + t * 8);
#pragma unroll
    for (int ks = 0; ks < 4; ++ks) {
        __syncthreads();                 // A2 writes (ks=0) / prior wf reads; drains prefetch
        *(uint4*)(Wt + wofs) = w20;
        *(uint4*)(Wt + 64 * 32 + wofs) = w21;
        __syncthreads();                 // Wt ready
        if (ks < 3) {                    // prefetch during MFMA phase (drains at next bar1)
            w20 = *(const uint4*)(We2S + (ks + 1) * 4096 + t * 8);
            w21 = *(const uint4*)(We2S + (ks + 1) * 4096 + 2048 + t * 8);
        }
        bf16x8_t af0 = *(const bf16x8_t*)(A2 + el0 * 136 + ks * 32 + q * 8);
        bf16x8_t af1 = *(const bf16x8_t*)(A2 + el1 * 136 + ks * 32 + q * 8);
#pragma unroll
        for (int ot = 0; ot < 8; ++ot) {
            bf16x8_t wf = *(const bf16x8_t*)(Wt + ot * (16 * 32) + rofs);
            acc[0][ot] = __builtin_amdgcn_mfma_f32_16x16x32_bf16(wf, af0, acc[0][ot], 0, 0, 0);
            acc[1][ot] = __builtin_amdgcn_mfma_f32_16x16x32_bf16(wf, af1, acc[1][ot], 0, 0, 0);
        }
    }

    // epilogue 2: + b, SiLU, * s[src]; gamma via q-lane shuffle reduce
    {
        float sg0 = s_sg[el0], sg1 = s_sg[el1];
        float gp0 = 0.f, gp1 = 0.f;
#pragma unroll
        for (int ot = 0; ot < 8; ++ot) {
            int oc = ot * 16 + q * 4;
            float4 b2 = *(const float4*)(be2 + oc);
            float4 wc = *(const float4*)(Wc + oc);
            f32x4_t v0_ = acc[0][ot], v1_ = acc[1][ot];
            v0_[0] = silu_f(v0_[0] + b2.x) * sg0; v0_[1] = silu_f(v0_[1] + b2.y) * sg0;
            v0_[2] = silu_f(v0_[2] + b2.z) * sg0; v0_[3] = silu_f(v0_[3] + b2.w) * sg0;
            v1_[0] = silu_f(v1_[0] + b2.x) * sg1; v1_[1] = silu_f(v1_[1] + b2.y) * sg1;
            v1_[2] = silu_f(v1_[2] + b2.z) * sg1; v1_[3] = silu_f(v1_[3] + b2.w) * sg1;
            acc[0][ot] = v0_; acc[1][ot] = v1_;
            gp0 += v0_[0] * wc.x + v0_[1] * wc.y + v0_[2] * wc.z + v0_[3] * wc.w;
            gp1 += v1_[0] * wc.x + v1_[1] * wc.y + v1_[2] * wc.z + v1_[3] * wc.w;
        }
        gp0 += __shfl_xor(gp0, 16); gp0 += __shfl_xor(gp0, 32);
        gp1 += __shfl_xor(gp1, 16); gp1 += __shfl_xor(gp1, 32);
        if (q == 0) {
            float b0 = bc[0];
            s_g[el0] = gp0 + b0;
            s_g[el1] = gp1 + b0;
        }
    }
    __syncthreads();   // P0: all A2 reads done (Mf aliases), s_g visible

    // coord: 24 threads, 3 axes x 8 row-chunks of 16 (atomics make chunk splits safe)
    if (t < 24) {
        int ax = t % 3, ch = t / 3;
        int base = ch * 16;
        float run = 0.f;
        int cur = s_dst[base];
        for (int r = 0; r < 16; ++r) {
            int rr = base + r;
            int d = s_dst[rr];
            if (d != cur) {
                atomicAdd(&coordsum[cur * 3 + ax], run);
                run = 0.f; cur = d;
            }
            run += s_g[rr] * s_diff[rr * 3 + ax];
        }
        atomicAdd(&coordsum[cur * 3 + ax], run);
    }

    // msum: two phases of 64 edges; all 256 threads (col x row-half), serial length 32
#pragma unroll
    for (int ph = 0; ph < 2; ++ph) {
        int lr = w * 16 + m_;
#pragma unroll
        for (int ot = 0; ot < 8; ++ot)
            *(f32x4_t*)(Mf + lr * 132 + ot * 16 + q * 4) = acc[ph][ot];
        __syncthreads();   // Mf complete
        {
            int c = t & 127;
            int half = t >> 7;               // wave-uniform (waves 0,1 -> 0; 2,3 -> 1)
            int base = ph * 64 + half * 32;
            float run = 0.f;
            int cur = s_dst[base];
            for (int r = 0; r < 32; ++r) {
                int d = s_dst[base + r];     // wave-uniform branch
                if (d != cur) {
                    atomicAdd(&msum[(long)cur * 128 + c], run);
                    run = 0.f; cur = d;
                }
                run += Mf[(half * 32 + r) * 132 + c];
            }
            atomicAdd(&msum[(long)cur * 128 + c], run);
        }
        __syncthreads();   // reduce done before Mf overwrite / exit
    }
}

// ---------------- node kernel v2: operand-swapped, no Abf staging, 4 blocks/CU ----------------
__global__ __launch_bounds__(256, 4)
void node_kernel(const __bf16* __restrict__ xb,
                 const float* __restrict__ msum,
                 const int* __restrict__ off,
                 const __bf16* __restrict__ Wn1S,
                 const float* __restrict__ bn1,
                 const __bf16* __restrict__ Wn2S,
                 const float* __restrict__ bn2,
                 const float* __restrict__ pos,
                 const float* __restrict__ csum,
                 float* __restrict__ xout,
                 float* __restrict__ pout) {
    __shared__ __align__(16) __bf16 Wt[128 * 32];   //  8,192 B
    __shared__ __align__(16) __bf16 A2[64 * 136];   // 17,408 B

    const int t = threadIdx.x;
    const int r0 = blockIdx.x * 64;
    const int w = t >> 6;
    const int lane = t & 63;
    const int m_ = lane & 15;
    const int q = lane >> 4;

    // pos update for this block's 64 nodes (independent of the MLP)
    if (t < 192) {
        int node = r0 + t / 3;
        if (node < NN) {
            int dg = off[node + 1] - off[node];
            float inv = 1.f / (float)(dg < 1 ? 1 : dg);
            int fl = node * 3 + t % 3;
            pout[fl] = pos[fl] + csum[fl] * inv;
        }
    }

    const int node = r0 + w * 16 + m_;
    const int ncl = node < NN ? node : NN - 1;
    const long nrow = (long)ncl * 128;
    const int dg = off[ncl + 1] - off[ncl];
    const float inv = 1.f / (float)(dg < 1 ? 1 : dg);

    f32x4_t acc[8];
#pragma unroll
    for (int ot = 0; ot < 8; ++ot) acc[ot] = (f32x4_t){0.f, 0.f, 0.f, 0.f};

    const int wrow = t >> 2;
    const int pch = (t & 3) ^ ((wrow >> 1) & 3);
    const int wofs = wrow * 32 + pch * 8;
    const int rofs = m_ * 32 + (q ^ ((m_ >> 1) & 3)) * 8;

    // ---- layer 1: K = 256; ks<4 from xb (bf16), ks>=4 from msum*inv (f32->bf16) ----
    bf16x8_t xf = *(const bf16x8_t*)(xb + nrow + q * 8);
    float4 mf0, mf1;
    uint4 v0 = *(const uint4*)(Wn1S + t * 8);
    uint4 v1 = *(const uint4*)(Wn1S + 2048 + t * 8);
#pragma unroll
    for (int ks = 0; ks < 8; ++ks) {
        __syncthreads();                 // prior Wt reads done
        *(uint4*)(Wt + wofs) = v0;
        *(uint4*)(Wt + 64 * 32 + wofs) = v1;
        __syncthreads();                 // Wt ready
        bf16x8_t nxf; float4 nm0, nm1;
        if (ks < 7) {                    // prefetch next slice + next input fragment
            v0 = *(const uint4*)(Wn1S + (ks + 1) * 4096 + t * 8);
            v1 = *(const uint4*)(Wn1S + (ks + 1) * 4096 + 2048 + t * 8);
            if (ks + 1 < 4) {
                nxf = *(const bf16x8_t*)(xb + nrow + (ks + 1) * 32 + q * 8);
            } else {
                const float* mp = msum + nrow + (ks + 1 - 4) * 32 + q * 8;
                nm0 = *(const float4*)(mp);
                nm1 = *(const float4*)(mp + 4);
            }
        }
        bf16x8_t cf;
        if (ks < 4) {
            cf = xf;
        } else {
            union { __bf16 h[8]; bf16x8_t v; } u;
            u.h[0] = (__bf16)(mf0.x * inv); u.h[1] = (__bf16)(mf0.y * inv);
            u.h[2] = (__bf16)(mf0.z * inv); u.h[3] = (__bf16)(mf0.w * inv);
            u.h[4] = (__bf16)(mf1.x * inv); u.h[5] = (__bf16)(mf1.y * inv);
            u.h[6] = (__bf16)(mf1.z * inv); u.h[7] = (__bf16)(mf1.w * inv);
            cf = u.v;
        }
#pragma unroll
        for (int ot = 0; ot < 8; ++ot) {
            bf16x8_t wf = *(const bf16x8_t*)(Wt + ot * (16 * 32) + rofs);
            acc[ot] = __builtin_amdgcn_mfma_f32_16x16x32_bf16(wf, cf, acc[ot], 0, 0, 0);
        }
        if (ks < 7) {
            if (ks + 1 < 4) xf = nxf;
            else { mf0 = nm0; mf1 = nm1; }
        }
    }

    // epilogue 1: + bn1, SiLU -> A2 (same-wave rows)
#pragma unroll
    for (int ot = 0; ot < 8; ++ot) {
        float4 b1 = *(const float4*)(bn1 + ot * 16 + q * 4);
        union { __bf16 h[4]; uint2 u; } pk;
        pk.h[0] = (__bf16)silu_f(acc[ot][0] + b1.x);
        pk.h[1] = (__bf16)silu_f(acc[ot][1] + b1.y);
        pk.h[2] = (__bf16)silu_f(acc[ot][2] + b1.z);
        pk.h[3] = (__bf16)silu_f(acc[ot][3] + b1.w);
        *(uint2*)(A2 + (w * 16 + m_) * 136 + ot * 16 + q * 4) = pk.u;
        acc[ot] = (f32x4_t){0.f, 0.f, 0.f, 0.f};
    }

    // ---- layer 2: K = 128, B-operand = A2 row fragments (same-wave LDS) ----
    uint4 u0 = *(const uint4*)(Wn2S + t * 8);
    uint4 u1 = *(const uint4*)(Wn2S + 2048 + t * 8);
#pragma unroll
    for (int ks = 0; ks < 4; ++ks) {
        __syncthreads();                 // prior Wt reads done
        *(uint4*)(Wt + wofs) = u0;
        *(uint4*)(Wt + 64 * 32 + wofs) = u1;
        __syncthreads();                 // Wt ready
        if (ks < 3) {
            u0 = *(const uint4*)(Wn2S + (ks + 1) * 4096 + t * 8);
            u1 = *(const uint4*)(Wn2S + (ks + 1) * 4096 + 2048 + t * 8);
        }
        bf16x8_t af = *(const bf16x8_t*)(A2 + (w * 16 + m_) * 136 + ks * 32 + q * 8);
#pragma unroll
        for (int ot = 0; ot < 8; ++ot) {
            bf16x8_t wf = *(const bf16x8_t*)(Wt + ot * (16 * 32) + rofs);
            acc[ot] = __builtin_amdgcn_mfma_f32_16x16x32_bf16(wf, af, acc[ot], 0, 0, 0);
        }
    }

    // epilogue 2: + bn2, coalesced float4 stores
    if (node < NN) {
#pragma unroll
        for (int ot = 0; ot < 8; ++ot) {
            float4 b2 = *(const float4*)(bn2 + ot * 16 + q * 4);
            float4 o;
            o.x = acc[ot][0] + b2.x; o.y = acc[ot][1] + b2.y;
            o.z = acc[ot][2] + b2.z; o.w = acc[ot][3] + b2.w;
            *(float4*)(xout + nrow + ot * 16 + q * 4) = o;
        }
    }
}

extern "C" void kernel_launch(void* const* d_in, const int* in_sizes, int n_in,
                              void* d_out, int out_size, void* d_ws, size_t ws_size,
                              hipStream_t stream) {
    const float* x     = (const float*)d_in[0];
    const float* pos   = (const float*)d_in[1];
    const int*   eidx  = (const int*)d_in[2];
    const float* eattr = (const float*)d_in[3];
    const float* s     = (const float*)d_in[4];
    const float* We1   = (const float*)d_in[5];
    const float* be1   = (const float*)d_in[6];
    const float* We2   = (const float*)d_in[7];
    const float* be2   = (const float*)d_in[8];
    const float* Wn1   = (const float*)d_in[9];
    const float* bn1   = (const float*)d_in[10];
    const float* Wn2   = (const float*)d_in[11];
    const float* bn2   = (const float*)d_in[12];
    const float* Wc    = (const float*)d_in[13];
    const float* bc    = (const float*)d_in[14];

    char* ws = (char*)d_ws;
    __bf16* xb     = (__bf16*)(ws);                 // 12,800,000
    __bf16* WyS    = (__bf16*)(ws + 12800000);      //     65,536
    __bf16* We2S   = (__bf16*)(ws + 12865536);      //     32,768
    __bf16* Wn1S   = (__bf16*)(ws + 12898304);      //     65,536
    __bf16* Wn2S   = (__bf16*)(ws + 12963840);      //     32,768
    float*  msum   = (float*)(ws + 12996608);       // 25,600,000
    float*  csum   = (float*)(ws + 38596608);       //    600,000
    int*    hist   = (int*)(ws + 39196608);         //    200,000
    int*    off    = (int*)(ws + 39396608);         //    200,064
    int*    cursor = (int*)(ws + 39596672);         //    200,064
    uint4*  erec   = (uint4*)(ws + 39796736);       // 25,600,000 (32B/edge)
    int*    bsum   = (int*)(ws + 65396736);         //      1,024
    __bf16* ya     = (__bf16*)(ws + 65397760);      // 12,800,000
    __bf16* yb     = (__bf16*)(ws + 78197760);      // 12,800,000 (end 90,997,760)

    float* xout = (float*)d_out;
    float* pout = xout + (size_t)NN * 128;

    // zero msum + csum + hist (contiguous, 26.4 MB)
    hipMemsetAsync(ws + 12996608, 0, 26400000, stream);
    prep_kernel<<<1024, 256, 0, stream>>>(x, We1, We2, Wn1, Wn2, eidx,
                                          xb, WyS, We2S, Wn1S, Wn2S, hist);
    ygemm_kernel<<<(NN + 63) / 64, 256, 0, stream>>>(xb, WyS, be1, ya, yb);
    scan_a<<<SCAN_BLOCKS, 256, 0, stream>>>(hist, bsum);
    scan_b<<<1, 256, 0, stream>>>(bsum);
    scan_c<<<SCAN_BLOCKS, 256, 0, stream>>>(hist, bsum, off, cursor);
    scatter_kernel<<<(EE + 255) / 256, 256, 0, stream>>>(eidx, pos, eattr, s, cursor, erec);
    edge_kernel<<<EE / 128, 256, 0, stream>>>(ya, yb, erec,
                                              We1, We2S, be2, Wc, bc,
                                              msum, csum);
    node_kernel<<<(NN + 63) / 64, 256, 0, stream>>>(xb, msum, off, Wn1S, bn1, Wn2S, bn2,
                                                    pos, csum, xout, pout);
}